// Round 5
// baseline (213.216 us; speedup 1.0000x reference)
//
#include <hip/hip_runtime.h>
#include <hip/hip_bf16.h>

#define EDGES  500000
#define NNODES 100000
#define QN     256
#define RN     401
#define DD     64
#define AA     64
#define OO     64
#define XSB    1563      // ceil(NNODES/64) blocks for xs/out phases
#define PB     1604      // (QN*RN)/64 blocks for p kernel (exact)
#define EB     15625     // EDGES/32 blocks for edge kernel (exact)
#define TB_H   3125      // k_tab blocks for hidden convert (+agg zero), exact
#define TB_Q   8         // q_emb convert (16384 elems, exact)
#define TB_R   13        // rela convert (25664 elems, guarded)
#define TB_W3  6         // W3 convert (12288 elems, exact)
#define TB_WS  2         // Ws convert (4096 elems, exact)
#define TABB   (TB_H + TB_Q + TB_R + TB_W3 + TB_WS)

typedef __attribute__((ext_vector_type(8))) short short8;
typedef __attribute__((ext_vector_type(2))) short short2v;
typedef __attribute__((ext_vector_type(4))) float f32x4;
typedef __attribute__((ext_vector_type(2))) float f32x2;
typedef __attribute__((ext_vector_type(4))) unsigned int uint4v;

__device__ inline unsigned short f2bf(float f) {
    union { float f; unsigned int u; } v; v.f = f;
    unsigned int u = v.u;
    u += 0x7FFFu + ((u >> 16) & 1u);   // round-to-nearest-even
    return (unsigned short)(u >> 16);
}

// pack two bf16 into a dword: lo -> [15:0], hi -> [31:16] (order by construction)
__device__ inline unsigned pack2bf(float lo, float hi) {
    return (unsigned)f2bf(lo) | ((unsigned)f2bf(hi) << 16);
}

__device__ inline f32x2 bfpair2f(unsigned int u) {
    union { unsigned int i; float f; } lo, hi;
    lo.i = u << 16;
    hi.i = u & 0xFFFF0000u;
    f32x2 r; r[0] = lo.f; r[1] = hi.f; return r;
}

__device__ inline short8 load8_cvt(const float* __restrict__ p) {
    f32x4 x0 = ((const f32x4*)p)[0];
    f32x4 x1 = ((const f32x4*)p)[1];
    short8 r;
    r[0] = (short)f2bf(x0[0]); r[1] = (short)f2bf(x0[1]);
    r[2] = (short)f2bf(x0[2]); r[3] = (short)f2bf(x0[3]);
    r[4] = (short)f2bf(x1[0]); r[5] = (short)f2bf(x1[1]);
    r[6] = (short)f2bf(x1[2]); r[7] = (short)f2bf(x1[3]);
    return r;
}

// elementwise product of two bf16x8 vectors, rounded back to bf16
__device__ inline short8 prod8_bf(const short* __restrict__ pa,
                                  const short* __restrict__ pb) {
    short8 a = *(const short8*)pa;
    short8 b = *(const short8*)pb;
    uint4v au = __builtin_bit_cast(uint4v, a);
    uint4v bu = __builtin_bit_cast(uint4v, b);
    uint4v ru;
#pragma unroll
    for (int j = 0; j < 4; ++j) {
        f32x2 x = bfpair2f(au[j]);
        f32x2 y = bfpair2f(bu[j]);
        ru[j] = pack2bf(x[0] * y[0], x[1] * y[1]);
    }
    return __builtin_bit_cast(short8, ru);
}

// packed bf16x2 atomic add (global_atomic_pk_add_bf16, gfx90a+/CDNA4)
__device__ inline void atomic_pk_add_bf16(short* addr, short2v v) {
#if __has_builtin(__builtin_amdgcn_global_atomic_fadd_v2bf16)
    __builtin_amdgcn_global_atomic_fadd_v2bf16(
        (__attribute__((address_space(1))) short2v*)addr, v);
#else
    asm volatile("global_atomic_pk_add_bf16 %0, %1, off"
                 :: "v"(addr), "v"(v) : "memory");
#endif
}

__device__ inline void atomic_pk_add_bf16_u(short* addr, unsigned v) {
    atomic_pk_add_bf16(addr, __builtin_bit_cast(short2v, v));
}

struct Params {
    const float* hidden; const float* Ws_W; const float* q_emb; const float* rela;
    const float* Wq_W;   const float* Wr_W; const float* Wqr_W; const float* Ws_b;
    const int*   edges;  const float* wa_W; const float* wa_b;  const float* Wh_W;
    short* Xs; short* hidden_bf; short* P; short* agg;
    short* q_bf; short* r_bf; short* w3_bf; short* ws_bf;   // scratch in out-head
    float* out; float* alpha_out;
};

// ---------------------------------------------------------------------------
// K_TAB: all f32->bf16 conversions, streamed once (BW-bound, coalesced):
//   [0,TB_H): hidden -> hidden_bf (8 elems/thread) + zero agg
//   then: q_emb -> q_bf, rela -> r_bf, [Wq|Wr|Wqr] -> w3_bf (row stride 192),
//         Ws -> ws_bf. Tables land in out-buffer scratch (overwritten by k_out).
// ---------------------------------------------------------------------------
__global__ void k_tab(Params pr) {
    int tid = threadIdx.x;
    int b = blockIdx.x;
    if (b < TB_H) {
        size_t idx = (size_t)b * 2048 + tid * 8;
        short8 v = load8_cvt(pr.hidden + idx);
        *(short8*)(pr.hidden_bf + idx) = v;
        *(short8*)(pr.agg + idx) = short8{0,0,0,0,0,0,0,0};
    } else if (b < TB_H + TB_Q) {
        int idx = (b - TB_H) * 2048 + tid * 8;            // < 16384, exact
        *(short8*)(pr.q_bf + idx) = load8_cvt(pr.q_emb + idx);
    } else if (b < TB_H + TB_Q + TB_R) {
        int idx = (b - TB_H - TB_Q) * 2048 + tid * 8;
        if (idx < RN * DD)                                 // 25664
            *(short8*)(pr.r_bf + idx) = load8_cvt(pr.rela + idx);
    } else if (b < TB_H + TB_Q + TB_R + TB_W3) {
        int idx = (b - TB_H - TB_Q - TB_R) * 2048 + tid * 8;  // < 12288, exact
        int a = idx / 192, k = idx - a * 192;              // 8-chunks never straddle
        const float* src = (k < 64)  ? pr.Wq_W  + a * 64 + k
                         : (k < 128) ? pr.Wr_W  + a * 64 + (k - 64)
                                     : pr.Wqr_W + a * 64 + (k - 128);
        *(short8*)(pr.w3_bf + idx) = load8_cvt(src);
    } else {
        int idx = (b - TB_H - TB_Q - TB_R - TB_W3) * 2048 + tid * 8;  // < 4096
        *(short8*)(pr.ws_bf + idx) = load8_cvt(pr.Ws_W + idx);
    }
}

// ---------------------------------------------------------------------------
// K_XS: Xs = hidden_bf @ ws_bf^T. A from hidden_bf (bf16, direct short8);
//       B from ws_bf scratch (8 KB, L1-resident) — no LDS staging, no barrier.
// ---------------------------------------------------------------------------
__global__ void k_xs(Params pr) {
    __shared__ short stage[4][16 * 72];    // per-wave 16x64 bf16 tile (+pad)
    int tid = threadIdx.x;
    int wave = tid >> 6, lane = tid & 63;
    int quad = lane >> 4, l15 = lane & 15;
    short* st = stage[wave];

    int rowbase = blockIdx.x * 64 + wave * 16;
    int row_a = rowbase + l15;
    f32x4 acc[4];
    for (int t = 0; t < 4; ++t) { acc[t][0]=acc[t][1]=acc[t][2]=acc[t][3]=0.f; }
#pragma unroll
    for (int ks = 0; ks < 2; ++ks) {
        int ka = ks * 32 + quad * 8;
        short8 afrag;
        if (row_a < NNODES) afrag = *(const short8*)(pr.hidden_bf + (size_t)row_a * DD + ka);
        else                afrag = short8{0,0,0,0,0,0,0,0};
#pragma unroll
        for (int t = 0; t < 4; ++t) {
            short8 bfrag = *(const short8*)(pr.ws_bf + (t * 16 + l15) * DD + ka);
            acc[t] = __builtin_amdgcn_mfma_f32_16x16x32_bf16(afrag, bfrag, acc[t], 0, 0, 0);
        }
    }
    // epilogue: stage -> wide stores (2 short8 stores/lane, coalesced)
#pragma unroll
    for (int t = 0; t < 4; ++t)
#pragma unroll
        for (int r = 0; r < 4; ++r)
            st[(quad * 4 + r) * 72 + t * 16 + l15] = (short)f2bf(acc[t][r]);
    asm volatile("s_waitcnt lgkmcnt(0)" ::: "memory");
#pragma unroll
    for (int i = 0; i < 2; ++i) {
        int rr = i * 8 + (lane >> 3);
        int cc = (lane & 7) * 8;
        int grow = rowbase + rr;
        if (grow < NNODES) {
            short8 v = *(short8*)&st[rr * 72 + cc];
            *(short8*)&pr.Xs[(size_t)grow * AA + cc] = v;
        }
    }
}

// ---------------------------------------------------------------------------
// K_P: P = Ws_b + concat(hq,hr,hq*hr) @ W3^T (K=192). hq/hr segments load
//      bf16 tables directly; only the product third converts. B from
//      w3_bf scratch (24.6 KB, L1/L2-resident), stride 192.
// ---------------------------------------------------------------------------
__global__ void k_p(Params pr) {
    __shared__ short stage[4][16 * 72];
    int tid = threadIdx.x;
    int wave = tid >> 6, lane = tid & 63;
    int quad = lane >> 4, l15 = lane & 15;
    short* st = stage[wave];

    int pairbase = blockIdx.x * 64 + wave * 16;
    int mypair = pairbase + l15;
    int q = mypair / RN;
    int r = mypair - q * RN;
    const short* hqb = pr.q_bf + (size_t)q * DD;
    const short* hrb = pr.r_bf + (size_t)r * DD;
    f32x4 acc[4];
#pragma unroll
    for (int t = 0; t < 4; ++t) {
        float b = pr.Ws_b[t * 16 + l15];
        acc[t][0] = acc[t][1] = acc[t][2] = acc[t][3] = b;
    }
#pragma unroll
    for (int ks = 0; ks < 6; ++ks) {
        int ka = ks * 32 + quad * 8;
        short8 afrag;
        if (ka < 64)       afrag = *(const short8*)(hqb + ka);
        else if (ka < 128) afrag = *(const short8*)(hrb + (ka - 64));
        else               afrag = prod8_bf(hqb + (ka - 128), hrb + (ka - 128));
#pragma unroll
        for (int t = 0; t < 4; ++t) {
            short8 bfrag = *(const short8*)(pr.w3_bf + (t * 16 + l15) * 192 + ka);
            acc[t] = __builtin_amdgcn_mfma_f32_16x16x32_bf16(afrag, bfrag, acc[t], 0, 0, 0);
        }
    }
    // epilogue: stage -> wide stores (no bounds check; PB grid is exact)
#pragma unroll
    for (int t = 0; t < 4; ++t)
#pragma unroll
        for (int rg = 0; rg < 4; ++rg)
            st[(quad * 4 + rg) * 72 + t * 16 + l15] = (short)f2bf(acc[t][rg]);
    asm volatile("s_waitcnt lgkmcnt(0)" ::: "memory");
#pragma unroll
    for (int i = 0; i < 2; ++i) {
        int rr = i * 8 + (lane >> 3);
        int cc = (lane & 7) * 8;
        int prow = pairbase + rr;
        short8 v = *(short8*)&st[rr * 72 + cc];
        *(short8*)&pr.P[(size_t)prow * AA + cc] = v;
    }
}

// ---------------------------------------------------------------------------
// K_EDGE: 8 edges per wave. Alpha phase: 8 lanes/edge, 16B loads, 3-step
//         reduce. Message phase: 4 passes of 32-lanes/edge so each atomic
//         instruction covers one edge's 128B agg row CONTIGUOUSLY
//         (lane -> base + lane*4B) — required for atomic write coalescing
//         (round-3 lesson: strided pk atomics cost ~16B HBM write each).
// ---------------------------------------------------------------------------
__global__ void k_edge(Params pr) {
    int tid  = threadIdx.x;
    int lane = tid & 63;
    int l8   = tid & 7;
    int g    = lane >> 3;                        // edge group within wave (0..7)
    int wave = tid >> 6;
    size_t ewave = (size_t)blockIdx.x * 32 + wave * 8;   // first edge of wave
    size_t e = ewave + g;                        // this group's edge

    // cooperative coalesced load of this wave's 8 edge rows (48 ints)
    const int* ebase = pr.edges + ewave * 6;
    int eval = (lane < 48) ? ebase[lane] : 0;
    int q   = __shfl(eval, g * 6 + 0, 64);
    int r   = __shfl(eval, g * 6 + 2, 64);
    int sub = __shfl(eval, g * 6 + 4, 64);
    int qr  = q * RN + r;
    int c8  = l8 * 8;

    // ---- alpha phase: 8 lanes/edge, 16B gathers of Xs/P rows ----
    short8 xs8 = *(const short8*)(pr.Xs + (size_t)sub * AA + c8);
    short8 pp8 = *(const short8*)(pr.P  + (size_t)qr  * AA + c8);
    f32x4 waA = *(const f32x4*)(pr.wa_W + c8);
    f32x4 waB = *(const f32x4*)(pr.wa_W + c8 + 4);

    uint4v xu = __builtin_bit_cast(uint4v, xs8);
    uint4v pu = __builtin_bit_cast(uint4v, pp8);
    f32x2 acc2; acc2[0] = 0.f; acc2[1] = 0.f;
#pragma unroll
    for (int j = 0; j < 4; ++j) {
        f32x2 a = bfpair2f(xu[j]);
        f32x2 b = bfpair2f(pu[j]);
        f32x2 s = a + b;                       // packable v_pk_add_f32
        float wlo = (j < 2) ? waA[2*j]     : waB[2*j - 4];
        float whi = (j < 2) ? waA[2*j + 1] : waB[2*j - 3];
        acc2[0] += fmaxf(s[0], 0.f) * wlo;
        acc2[1] += fmaxf(s[1], 0.f) * whi;
    }
    float v = acc2[0] + acc2[1];
    v += __shfl_xor(v, 1, 64);
    v += __shfl_xor(v, 2, 64);
    v += __shfl_xor(v, 4, 64);
    float alpha = 1.f / (1.f + __expf(-(v + pr.wa_b[0])));
    if (l8 == 0) pr.alpha_out[e] = alpha;

    // ---- message phase: 4 passes, 32 lanes/edge, contiguous atomics ----
    int half = lane >> 5;                        // 0..1: which edge this pass
    int c2   = (lane & 31) * 2;                  // contiguous column pair
#pragma unroll
    for (int pass = 0; pass < 4; ++pass) {
        int ge    = pass * 2 + half;             // edge group handled this pass
        int sub_p = __shfl(eval, ge * 6 + 4, 64);
        int r_p   = __shfl(eval, ge * 6 + 2, 64);
        int obj_p = __shfl(eval, ge * 6 + 5, 64);
        float al  = __shfl(alpha, ge * 8, 64);   // all lanes of group ge hold alpha
        unsigned hs_u = *(const unsigned*)&pr.hidden_bf[(size_t)sub_p * DD + c2];
        f32x2 hs = bfpair2f(hs_u);
        f32x2 hr = *(const f32x2*)&pr.rela[(size_t)r_p * DD + c2];
        atomic_pk_add_bf16_u(pr.agg + (size_t)obj_p * DD + c2,
                             pack2bf(al * hs[0] * hr[0], al * hs[1] * hr[1]));
    }
}

// ---------------------------------------------------------------------------
// K_OUT: out = agg @ Wh^T (MFMA, K=64; agg bf16). LDS-staged f32x4 stores.
//        Wh staged in-kernel (must NOT read out-scratch: k_out writes out).
// ---------------------------------------------------------------------------
__global__ void k_out(Params pr) {
    __shared__ short W[OO * 72];           // 9216 B
    __shared__ float stF[4][16 * 68];      // 17408 B, per-wave 16x64 f32 tile (+pad)
    int tid = threadIdx.x;
    for (int idx = tid; idx < (OO * DD) / 2; idx += 256) {
        int o = idx >> 5, d2 = (idx & 31) * 2;
        f32x2 x = *(const f32x2*)(pr.Wh_W + o * 64 + d2);
        *reinterpret_cast<unsigned*>(&W[o * 72 + d2]) = pack2bf(x[0], x[1]);
    }
    __syncthreads();
    int wave = tid >> 6, lane = tid & 63;
    int quad = lane >> 4, l15 = lane & 15;
    int rowbase = blockIdx.x * 64 + wave * 16;
    int row_a = rowbase + l15;
    float* st = stF[wave];

    f32x4 acc[4];
    for (int t = 0; t < 4; ++t) { acc[t][0]=acc[t][1]=acc[t][2]=acc[t][3]=0.f; }
#pragma unroll
    for (int ks = 0; ks < 2; ++ks) {
        int ka = ks * 32 + quad * 8;
        short8 afrag;
        if (row_a < NNODES) afrag = *(const short8*)(pr.agg + (size_t)row_a * DD + ka);
        else                afrag = short8{0,0,0,0,0,0,0,0};
#pragma unroll
        for (int t = 0; t < 4; ++t) {
            short8 bfrag = *(const short8*)&W[(t * 16 + l15) * 72 + ka];
            acc[t] = __builtin_amdgcn_mfma_f32_16x16x32_bf16(afrag, bfrag, acc[t], 0, 0, 0);
        }
    }
    // epilogue: stage -> 4 coalesced f32x4 stores/lane
#pragma unroll
    for (int t = 0; t < 4; ++t)
#pragma unroll
        for (int r = 0; r < 4; ++r)
            st[(quad * 4 + r) * 68 + t * 16 + l15] = acc[t][r];
    asm volatile("s_waitcnt lgkmcnt(0)" ::: "memory");
#pragma unroll
    for (int i = 0; i < 4; ++i) {
        int rr = i * 4 + (lane >> 4);
        int cc = (lane & 15) * 4;
        int grow = rowbase + rr;
        if (grow < NNODES) {
            f32x4 v = *(f32x4*)&st[rr * 68 + cc];
            *(f32x4*)&pr.out[(size_t)grow * OO + cc] = v;
        }
    }
}

// ---------------------------------------------------------------------------
extern "C" void kernel_launch(void* const* d_in, const int* in_sizes, int n_in,
                              void* d_out, int out_size, void* d_ws, size_t ws_size,
                              hipStream_t stream) {
    Params pr;
    pr.q_emb  = (const float*)d_in[1];
    pr.rela   = (const float*)d_in[2];
    pr.hidden = (const float*)d_in[3];
    pr.edges  = (const int*)d_in[4];
    pr.Ws_W   = (const float*)d_in[6];
    pr.Ws_b   = (const float*)d_in[7];
    pr.Wr_W   = (const float*)d_in[8];
    pr.Wq_W   = (const float*)d_in[9];
    pr.Wqr_W  = (const float*)d_in[10];
    pr.wa_W   = (const float*)d_in[11];
    pr.wa_b   = (const float*)d_in[12];
    pr.Wh_W   = (const float*)d_in[13];

    short* Xs        = (short*)d_ws;                         // N*A   bf16
    short* P         = Xs + (size_t)NNODES * AA;             // Q*R*A bf16
    short* hidden_bf = P + (size_t)QN * RN * AA;             // N*D   bf16
    short* agg       = hidden_bf + (size_t)NNODES * DD;      // N*D   bf16
    pr.Xs = Xs; pr.P = P; pr.hidden_bf = hidden_bf; pr.agg = agg;

    pr.out       = (float*)d_out;                            // hidden_new (N*O)
    pr.alpha_out = pr.out + (size_t)NNODES * OO;             // alpha (E)

    // bf16 tables in out-buffer head (117 KB scratch; k_tab writes, k_xs/k_p
    // read, k_out fully overwrites afterwards — safe by stream ordering).
    short* scr = (short*)d_out;
    pr.q_bf  = scr;                        // 16384 shorts
    pr.r_bf  = pr.q_bf  + QN * DD;         // 25664 shorts
    pr.w3_bf = pr.r_bf  + RN * DD;         // 12288 shorts (stride 192)
    pr.ws_bf = pr.w3_bf + AA * 192;        // 4096 shorts

    k_tab<<<TABB, 256, 0, stream>>>(pr);
    k_xs <<<XSB,  256, 0, stream>>>(pr);
    k_p  <<<PB,   256, 0, stream>>>(pr);
    k_edge<<<EB,  256, 0, stream>>>(pr);
    k_out<<<XSB,  256, 0, stream>>>(pr);
}

// Round 6
// 195.216 us; speedup vs baseline: 1.0922x; 1.0922x over previous
//
#include <hip/hip_runtime.h>
#include <hip/hip_bf16.h>

#define EDGES  500000
#define NNODES 100000
#define QN     256
#define RN     401
#define DD     64
#define AA     64
#define OO     64
#define XSB    1563      // ceil(NNODES/64) blocks for xs/out phases
#define PB     1604      // (QN*RN)/64 blocks for p-phase (exact)
#define RBB    13        // rela->bf16 convert blocks (25664 elems, guarded)
#define EB     15625     // EDGES/32 blocks for edge kernel (exact)

typedef __attribute__((ext_vector_type(8))) short short8;
typedef __attribute__((ext_vector_type(2))) short short2v;
typedef __attribute__((ext_vector_type(4))) float f32x4;
typedef __attribute__((ext_vector_type(2))) float f32x2;
typedef __attribute__((ext_vector_type(4))) unsigned int uint4v;

__device__ inline unsigned short f2bf(float f) {
    union { float f; unsigned int u; } v; v.f = f;
    unsigned int u = v.u;
    u += 0x7FFFu + ((u >> 16) & 1u);   // round-to-nearest-even
    return (unsigned short)(u >> 16);
}

// pack two bf16 into a dword: lo -> [15:0], hi -> [31:16] (order by construction)
__device__ inline unsigned pack2bf(float lo, float hi) {
    return (unsigned)f2bf(lo) | ((unsigned)f2bf(hi) << 16);
}

__device__ inline f32x2 bfpair2f(unsigned int u) {
    union { unsigned int i; float f; } lo, hi;
    lo.i = u << 16;
    hi.i = u & 0xFFFF0000u;
    f32x2 r; r[0] = lo.f; r[1] = hi.f; return r;
}

__device__ inline short8 load8_cvt(const float* __restrict__ p) {
    f32x4 x0 = ((const f32x4*)p)[0];
    f32x4 x1 = ((const f32x4*)p)[1];
    short8 r;
    r[0] = (short)f2bf(x0[0]); r[1] = (short)f2bf(x0[1]);
    r[2] = (short)f2bf(x0[2]); r[3] = (short)f2bf(x0[3]);
    r[4] = (short)f2bf(x1[0]); r[5] = (short)f2bf(x1[1]);
    r[6] = (short)f2bf(x1[2]); r[7] = (short)f2bf(x1[3]);
    return r;
}

__device__ inline short8 load8_cvt_prod(const float* __restrict__ pa,
                                        const float* __restrict__ pb) {
    f32x4 a0 = ((const f32x4*)pa)[0];
    f32x4 a1 = ((const f32x4*)pa)[1];
    f32x4 b0 = ((const f32x4*)pb)[0];
    f32x4 b1 = ((const f32x4*)pb)[1];
    short8 r;
    r[0] = (short)f2bf(a0[0]*b0[0]); r[1] = (short)f2bf(a0[1]*b0[1]);
    r[2] = (short)f2bf(a0[2]*b0[2]); r[3] = (short)f2bf(a0[3]*b0[3]);
    r[4] = (short)f2bf(a1[0]*b1[0]); r[5] = (short)f2bf(a1[1]*b1[1]);
    r[6] = (short)f2bf(a1[2]*b1[2]); r[7] = (short)f2bf(a1[3]*b1[3]);
    return r;
}

// packed bf16x2 atomic add (global_atomic_pk_add_bf16, gfx90a+/CDNA4)
__device__ inline void atomic_pk_add_bf16(short* addr, short2v v) {
#if __has_builtin(__builtin_amdgcn_global_atomic_fadd_v2bf16)
    __builtin_amdgcn_global_atomic_fadd_v2bf16(
        (__attribute__((address_space(1))) short2v*)addr, v);
#else
    asm volatile("global_atomic_pk_add_bf16 %0, %1, off"
                 :: "v"(addr), "v"(v) : "memory");
#endif
}

__device__ inline void atomic_pk_add_bf16_u(short* addr, unsigned v) {
    atomic_pk_add_bf16(addr, __builtin_bit_cast(short2v, v));
}

struct Params {
    const float* hidden; const float* Ws_W; const float* q_emb; const float* rela;
    const float* Wq_W;   const float* Wr_W; const float* Wqr_W; const float* Ws_b;
    const int*   edges;  const float* wa_W; const float* wa_b;  const float* Wh_W;
    short* Xs; short* hidden_bf; short* P; short* agg;
    short* r_bf;                                   // bf16 rela table (out-head scratch)
    float* out; float* alpha_out;
};

// ---------------------------------------------------------------------------
// K_PRE: blocks [0,XSB): Xs = hidden @ Ws^T + hidden_bf + zero agg.
//        blocks [XSB,XSB+PB): P = Ws_b + concat(hq,hr,hq*hr) @ W3^T (K=192).
//        blocks [XSB+PB,+RBB): rela -> r_bf (consumed only by later k_edge).
// Epilogues: C-fragments -> LDS tile -> coalesced short8 stores (2/lane).
// ---------------------------------------------------------------------------
__global__ void k_pre(Params pr) {
    __shared__ short W[AA * 200];          // 25600 B (xs phase uses 72-stride part)
    __shared__ short stage[4][16 * 72];    // 9216 B, per-wave 16x64 bf16 tile (+pad)
    int tid = threadIdx.x;
    int wave = tid >> 6, lane = tid & 63;
    int quad = lane >> 4, l15 = lane & 15;
    short* st = stage[wave];

    if (blockIdx.x < XSB) {
        // ---------------- xs phase ----------------
        int rowbase_blk = blockIdx.x * 64;
        {   // zero agg rows owned by this block (wide stores)
            const short8 z = short8{0,0,0,0,0,0,0,0};
            int base = rowbase_blk * DD + tid * 16;
            int row0 = rowbase_blk + (tid >> 2);
            if (row0 < NNODES) {
                *(short8*)(pr.agg + base) = z;
                *(short8*)(pr.agg + base + 8) = z;
            }
        }
        // stage Ws as bf16 (division-free, f32x2 loads, dword LDS stores)
        for (int idx = tid; idx < (AA * DD) / 2; idx += 256) {
            int a = idx >> 5, d2 = (idx & 31) * 2;
            f32x2 x = *(const f32x2*)(pr.Ws_W + a * 64 + d2);
            *reinterpret_cast<unsigned*>(&W[a * 72 + d2]) = pack2bf(x[0], x[1]);
        }
        __syncthreads();
        int rowbase = rowbase_blk + wave * 16;
        int row_a = rowbase + l15;
        f32x4 acc[4];
        for (int t = 0; t < 4; ++t) { acc[t][0]=acc[t][1]=acc[t][2]=acc[t][3]=0.f; }
#pragma unroll
        for (int ks = 0; ks < 2; ++ks) {
            int ka = ks * 32 + quad * 8;
            short8 afrag;
            if (row_a < NNODES) {
                afrag = load8_cvt(pr.hidden + (size_t)row_a * DD + ka);
                *(short8*)(pr.hidden_bf + (size_t)row_a * DD + ka) = afrag;
            } else {
                afrag = short8{0,0,0,0,0,0,0,0};
            }
#pragma unroll
            for (int t = 0; t < 4; ++t) {
                short8 bfrag = *(const short8*)&W[(t * 16 + l15) * 72 + ka];
                acc[t] = __builtin_amdgcn_mfma_f32_16x16x32_bf16(afrag, bfrag, acc[t], 0, 0, 0);
            }
        }
        // epilogue: stage -> wide stores (2 short8 stores/lane, coalesced)
#pragma unroll
        for (int t = 0; t < 4; ++t)
#pragma unroll
            for (int r = 0; r < 4; ++r)
                st[(quad * 4 + r) * 72 + t * 16 + l15] = (short)f2bf(acc[t][r]);
        asm volatile("s_waitcnt lgkmcnt(0)" ::: "memory");
#pragma unroll
        for (int i = 0; i < 2; ++i) {
            int rr = i * 8 + (lane >> 3);
            int cc = (lane & 7) * 8;
            int grow = rowbase + rr;
            if (grow < NNODES) {
                short8 v = *(short8*)&st[rr * 72 + cc];
                *(short8*)&pr.Xs[(size_t)grow * AA + cc] = v;
            }
        }
    } else if (blockIdx.x < XSB + PB) {
        // ---------------- p phase ----------------
        int pb = blockIdx.x - XSB;
        // stage W3 = [Wq|Wr|Wqr] as bf16, division-free, f32x2 + manual pack
#pragma unroll
        for (int m = 0; m < 3; ++m) {
            const float* src = (m == 0) ? pr.Wq_W : (m == 1) ? pr.Wr_W : pr.Wqr_W;
            for (int idx = tid; idx < (AA * DD) / 2; idx += 256) {
                int a = idx >> 5, d2 = (idx & 31) * 2;
                f32x2 x = *(const f32x2*)(src + a * 64 + d2);
                *reinterpret_cast<unsigned*>(&W[a * 200 + m * 64 + d2]) =
                    pack2bf(x[0], x[1]);
            }
        }
        __syncthreads();
        int pairbase = pb * 64 + wave * 16;
        int mypair = pairbase + l15;
        int q = mypair / RN;
        int r = mypair - q * RN;
        const float* hq = pr.q_emb + (size_t)q * DD;
        const float* hr = pr.rela  + (size_t)r * DD;
        f32x4 acc[4];
#pragma unroll
        for (int t = 0; t < 4; ++t) {
            float b = pr.Ws_b[t * 16 + l15];
            acc[t][0] = acc[t][1] = acc[t][2] = acc[t][3] = b;
        }
#pragma unroll
        for (int ks = 0; ks < 6; ++ks) {
            int ka = ks * 32 + quad * 8;
            short8 afrag;
            if (ka < 64)       afrag = load8_cvt(hq + ka);
            else if (ka < 128) afrag = load8_cvt(hr + (ka - 64));
            else               afrag = load8_cvt_prod(hq + (ka - 128), hr + (ka - 128));
#pragma unroll
            for (int t = 0; t < 4; ++t) {
                short8 bfrag = *(const short8*)&W[(t * 16 + l15) * 200 + ka];
                acc[t] = __builtin_amdgcn_mfma_f32_16x16x32_bf16(afrag, bfrag, acc[t], 0, 0, 0);
            }
        }
        // epilogue: stage -> wide stores (no bounds check; PB grid is exact)
#pragma unroll
        for (int t = 0; t < 4; ++t)
#pragma unroll
            for (int rg = 0; rg < 4; ++rg)
                st[(quad * 4 + rg) * 72 + t * 16 + l15] = (short)f2bf(acc[t][rg]);
        asm volatile("s_waitcnt lgkmcnt(0)" ::: "memory");
#pragma unroll
        for (int i = 0; i < 2; ++i) {
            int rr = i * 8 + (lane >> 3);
            int cc = (lane & 7) * 8;
            int prow = pairbase + rr;
            short8 v = *(short8*)&st[rr * 72 + cc];
            *(short8*)&pr.P[(size_t)prow * AA + cc] = v;
        }
    } else {
        // ---------------- rela -> bf16 table (for k_edge only) ----------------
        int idx = (blockIdx.x - (XSB + PB)) * 2048 + tid * 8;
        if (idx < RN * DD)
            *(short8*)(pr.r_bf + idx) = load8_cvt(pr.rela + idx);
    }
}

// ---------------------------------------------------------------------------
// K_EDGE: 8 edges per wave. All message-phase indices + hs/hr gathers hoisted
//         ABOVE the alpha computation (independent of alpha) so HBM/L3 latency
//         overlaps the reduce+sigmoid. Alpha phase: 8 lanes/edge, 16B loads,
//         3-step reduce. Message phase: 4 passes of 32-lanes/edge so each
//         atomic instruction covers one edge's 128B agg row CONTIGUOUSLY
//         (round-3 lesson: strided pk atomics cost ~16B HBM write each).
// ---------------------------------------------------------------------------
__global__ void k_edge(Params pr) {
    int tid  = threadIdx.x;
    int lane = tid & 63;
    int l8   = tid & 7;
    int g    = lane >> 3;                        // edge group within wave (0..7)
    int wave = tid >> 6;
    size_t ewave = (size_t)blockIdx.x * 32 + wave * 8;   // first edge of wave

    // cooperative coalesced load of this wave's 8 edge rows (48 ints)
    const int* ebase = pr.edges + ewave * 6;
    int eval = (lane < 48) ? ebase[lane] : 0;
    int q   = __shfl(eval, g * 6 + 0, 64);
    int r   = __shfl(eval, g * 6 + 2, 64);
    int sub = __shfl(eval, g * 6 + 4, 64);
    int qr  = q * RN + r;
    int c8  = l8 * 8;

    // ---- issue alpha-phase gathers (16B/lane) ----
    short8 xs8 = *(const short8*)(pr.Xs + (size_t)sub * AA + c8);
    short8 pp8 = *(const short8*)(pr.P  + (size_t)qr  * AA + c8);
    f32x4 waA = *(const f32x4*)(pr.wa_W + c8);
    f32x4 waB = *(const f32x4*)(pr.wa_W + c8 + 4);

    // ---- hoist message-phase indices + gathers (independent of alpha) ----
    int half = lane >> 5;                        // which edge of the pair/pass
    int c2   = (lane & 31) * 2;                  // contiguous column pair
    int objs[4];
    unsigned hs_u[4], hr_u[4];
#pragma unroll
    for (int pass = 0; pass < 4; ++pass) {
        int ge    = pass * 2 + half;
        int sub_p = __shfl(eval, ge * 6 + 4, 64);
        int r_p   = __shfl(eval, ge * 6 + 2, 64);
        objs[pass] = __shfl(eval, ge * 6 + 5, 64);
        hs_u[pass] = *(const unsigned*)&pr.hidden_bf[(size_t)sub_p * DD + c2];
        hr_u[pass] = *(const unsigned*)&pr.r_bf[(size_t)r_p * DD + c2];
    }

    // ---- alpha compute (overlaps the gathers above) ----
    uint4v xu = __builtin_bit_cast(uint4v, xs8);
    uint4v pu = __builtin_bit_cast(uint4v, pp8);
    f32x2 acc2; acc2[0] = 0.f; acc2[1] = 0.f;
#pragma unroll
    for (int j = 0; j < 4; ++j) {
        f32x2 a = bfpair2f(xu[j]);
        f32x2 b = bfpair2f(pu[j]);
        f32x2 s = a + b;                       // packable v_pk_add_f32
        float wlo = (j < 2) ? waA[2*j]     : waB[2*j - 4];
        float whi = (j < 2) ? waA[2*j + 1] : waB[2*j - 3];
        acc2[0] += fmaxf(s[0], 0.f) * wlo;
        acc2[1] += fmaxf(s[1], 0.f) * whi;
    }
    float v = acc2[0] + acc2[1];
    v += __shfl_xor(v, 1, 64);
    v += __shfl_xor(v, 2, 64);
    v += __shfl_xor(v, 4, 64);
    float alpha = 1.f / (1.f + __expf(-(v + pr.wa_b[0])));

    // coalesced alpha store: lanes 0..7 write 8 contiguous floats
    float a_st = __shfl(alpha, (lane & 7) * 8, 64);
    if (lane < 8) pr.alpha_out[ewave + lane] = a_st;

    // ---- message phase: 4 passes, 32 lanes/edge, contiguous atomics ----
#pragma unroll
    for (int pass = 0; pass < 4; ++pass) {
        int ge   = pass * 2 + half;
        float al = __shfl(alpha, ge * 8, 64);    // lane ge*8 holds edge ge's alpha
        f32x2 hs = bfpair2f(hs_u[pass]);
        f32x2 hr = bfpair2f(hr_u[pass]);
        atomic_pk_add_bf16_u(pr.agg + (size_t)objs[pass] * DD + c2,
                             pack2bf(al * hs[0] * hr[0], al * hs[1] * hr[1]));
    }
}

// ---------------------------------------------------------------------------
// K_OUT: out = agg @ Wh^T (MFMA, K=64; agg bf16). LDS-staged f32x4 stores.
// ---------------------------------------------------------------------------
__global__ void k_out(Params pr) {
    __shared__ short W[OO * 72];           // 9216 B
    __shared__ float stF[4][16 * 68];      // 17408 B, per-wave 16x64 f32 tile (+pad)
    int tid = threadIdx.x;
    for (int idx = tid; idx < (OO * DD) / 2; idx += 256) {
        int o = idx >> 5, d2 = (idx & 31) * 2;
        f32x2 x = *(const f32x2*)(pr.Wh_W + o * 64 + d2);
        *reinterpret_cast<unsigned*>(&W[o * 72 + d2]) = pack2bf(x[0], x[1]);
    }
    __syncthreads();
    int wave = tid >> 6, lane = tid & 63;
    int quad = lane >> 4, l15 = lane & 15;
    int rowbase = blockIdx.x * 64 + wave * 16;
    int row_a = rowbase + l15;
    float* st = stF[wave];

    f32x4 acc[4];
    for (int t = 0; t < 4; ++t) { acc[t][0]=acc[t][1]=acc[t][2]=acc[t][3]=0.f; }
#pragma unroll
    for (int ks = 0; ks < 2; ++ks) {
        int ka = ks * 32 + quad * 8;
        short8 afrag;
        if (row_a < NNODES) afrag = *(const short8*)(pr.agg + (size_t)row_a * DD + ka);
        else                afrag = short8{0,0,0,0,0,0,0,0};
#pragma unroll
        for (int t = 0; t < 4; ++t) {
            short8 bfrag = *(const short8*)&W[(t * 16 + l15) * 72 + ka];
            acc[t] = __builtin_amdgcn_mfma_f32_16x16x32_bf16(afrag, bfrag, acc[t], 0, 0, 0);
        }
    }
    // epilogue: stage -> 4 coalesced f32x4 stores/lane
#pragma unroll
    for (int t = 0; t < 4; ++t)
#pragma unroll
        for (int r = 0; r < 4; ++r)
            st[(quad * 4 + r) * 68 + t * 16 + l15] = acc[t][r];
    asm volatile("s_waitcnt lgkmcnt(0)" ::: "memory");
#pragma unroll
    for (int i = 0; i < 4; ++i) {
        int rr = i * 4 + (lane >> 4);
        int cc = (lane & 15) * 4;
        int grow = rowbase + rr;
        if (grow < NNODES) {
            f32x4 v = *(f32x4*)&st[rr * 68 + cc];
            *(f32x4*)&pr.out[(size_t)grow * OO + cc] = v;
        }
    }
}

// ---------------------------------------------------------------------------
extern "C" void kernel_launch(void* const* d_in, const int* in_sizes, int n_in,
                              void* d_out, int out_size, void* d_ws, size_t ws_size,
                              hipStream_t stream) {
    Params pr;
    pr.q_emb  = (const float*)d_in[1];
    pr.rela   = (const float*)d_in[2];
    pr.hidden = (const float*)d_in[3];
    pr.edges  = (const int*)d_in[4];
    pr.Ws_W   = (const float*)d_in[6];
    pr.Ws_b   = (const float*)d_in[7];
    pr.Wr_W   = (const float*)d_in[8];
    pr.Wq_W   = (const float*)d_in[9];
    pr.Wqr_W  = (const float*)d_in[10];
    pr.wa_W   = (const float*)d_in[11];
    pr.wa_b   = (const float*)d_in[12];
    pr.Wh_W   = (const float*)d_in[13];

    short* Xs        = (short*)d_ws;                         // N*A   bf16
    short* P         = Xs + (size_t)NNODES * AA;             // Q*R*A bf16
    short* hidden_bf = P + (size_t)QN * RN * AA;             // N*D   bf16
    short* agg       = hidden_bf + (size_t)NNODES * DD;      // N*D   bf16
    pr.Xs = Xs; pr.P = P; pr.hidden_bf = hidden_bf; pr.agg = agg;

    pr.out       = (float*)d_out;                            // hidden_new (N*O)
    pr.alpha_out = pr.out + (size_t)NNODES * OO;             // alpha (E)

    // r_bf table in out-buffer head (51 KB scratch; written by k_pre tail
    // blocks, read only by k_edge, overwritten by k_out — safe by ordering).
    pr.r_bf = (short*)d_out;

    k_pre<<<XSB + PB + RBB, 256, 0, stream>>>(pr);
    k_edge<<<EB, 256, 0, stream>>>(pr);
    k_out<<<XSB, 256, 0, stream>>>(pr);
}

// Round 7
// 193.929 us; speedup vs baseline: 1.0995x; 1.0066x over previous
//
#include <hip/hip_runtime.h>
#include <hip/hip_bf16.h>

#define EDGES  500000
#define NNODES 100000
#define QN     256
#define RN     401
#define DD     64
#define AA     64
#define OO     64
#define XSB4   391       // ceil(NNODES/256) blocks, 256 rows each (xs phase)
#define PB4    401       // (QN*RN)/256 blocks, 256 pairs each (exact)
#define OB4    391       // ceil(NNODES/256) blocks (k_out)
#define EB     15625     // EDGES/32 blocks for edge kernel (exact)

typedef __attribute__((ext_vector_type(8))) short short8;
typedef __attribute__((ext_vector_type(2))) short short2v;
typedef __attribute__((ext_vector_type(4))) float f32x4;
typedef __attribute__((ext_vector_type(2))) float f32x2;
typedef __attribute__((ext_vector_type(4))) unsigned int uint4v;

__device__ inline unsigned short f2bf(float f) {
    union { float f; unsigned int u; } v; v.f = f;
    unsigned int u = v.u;
    u += 0x7FFFu + ((u >> 16) & 1u);   // round-to-nearest-even
    return (unsigned short)(u >> 16);
}

// pack two bf16 into a dword: lo -> [15:0], hi -> [31:16] (order by construction)
__device__ inline unsigned pack2bf(float lo, float hi) {
    return (unsigned)f2bf(lo) | ((unsigned)f2bf(hi) << 16);
}

__device__ inline f32x2 bfpair2f(unsigned int u) {
    union { unsigned int i; float f; } lo, hi;
    lo.i = u << 16;
    hi.i = u & 0xFFFF0000u;
    f32x2 r; r[0] = lo.f; r[1] = hi.f; return r;
}

__device__ inline short8 load8_cvt(const float* __restrict__ p) {
    f32x4 x0 = ((const f32x4*)p)[0];
    f32x4 x1 = ((const f32x4*)p)[1];
    short8 r;
    r[0] = (short)f2bf(x0[0]); r[1] = (short)f2bf(x0[1]);
    r[2] = (short)f2bf(x0[2]); r[3] = (short)f2bf(x0[3]);
    r[4] = (short)f2bf(x1[0]); r[5] = (short)f2bf(x1[1]);
    r[6] = (short)f2bf(x1[2]); r[7] = (short)f2bf(x1[3]);
    return r;
}

__device__ inline short8 load8_cvt_prod(const float* __restrict__ pa,
                                        const float* __restrict__ pb) {
    f32x4 a0 = ((const f32x4*)pa)[0];
    f32x4 a1 = ((const f32x4*)pa)[1];
    f32x4 b0 = ((const f32x4*)pb)[0];
    f32x4 b1 = ((const f32x4*)pb)[1];
    short8 r;
    r[0] = (short)f2bf(a0[0]*b0[0]); r[1] = (short)f2bf(a0[1]*b0[1]);
    r[2] = (short)f2bf(a0[2]*b0[2]); r[3] = (short)f2bf(a0[3]*b0[3]);
    r[4] = (short)f2bf(a1[0]*b1[0]); r[5] = (short)f2bf(a1[1]*b1[1]);
    r[6] = (short)f2bf(a1[2]*b1[2]); r[7] = (short)f2bf(a1[3]*b1[3]);
    return r;
}

// packed bf16x2 atomic add (global_atomic_pk_add_bf16, gfx90a+/CDNA4)
__device__ inline void atomic_pk_add_bf16(short* addr, short2v v) {
#if __has_builtin(__builtin_amdgcn_global_atomic_fadd_v2bf16)
    __builtin_amdgcn_global_atomic_fadd_v2bf16(
        (__attribute__((address_space(1))) short2v*)addr, v);
#else
    asm volatile("global_atomic_pk_add_bf16 %0, %1, off"
                 :: "v"(addr), "v"(v) : "memory");
#endif
}

__device__ inline void atomic_pk_add_bf16_u(short* addr, unsigned v) {
    atomic_pk_add_bf16(addr, __builtin_bit_cast(short2v, v));
}

struct Params {
    const float* hidden; const float* Ws_W; const float* q_emb; const float* rela;
    const float* Wq_W;   const float* Wr_W; const float* Wqr_W; const float* Ws_b;
    const int*   edges;  const float* wa_W; const float* wa_b;  const float* Wh_W;
    short* Xs; short* hidden_bf; short* P; short* agg;
    float* out; float* alpha_out;
};

// ---------------------------------------------------------------------------
// K_PRE: blocks [0,XSB4): 256 rows each — Xs = hidden @ Ws^T + hidden_bf +
//          zero agg; Ws staged ONCE per block, 4 row-tile iterations.
//        blocks [XSB4,XSB4+PB4): 256 pairs each — P = Ws_b +
//          concat(hq,hr,hq*hr) @ W3^T; W3 staged ONCE, 4 pair-tile iterations.
// Staging amortized 4x vs the 64-row/block version (round-6 theory).
// ---------------------------------------------------------------------------
__global__ void k_pre(Params pr) {
    __shared__ short W[AA * 200];          // 25600 B (xs phase uses 72-stride part)
    __shared__ short stage[4][16 * 72];    // 9216 B, per-wave 16x64 bf16 tile (+pad)
    int tid = threadIdx.x;
    int wave = tid >> 6, lane = tid & 63;
    int quad = lane >> 4, l15 = lane & 15;
    short* st = stage[wave];

    if (blockIdx.x < XSB4) {
        // ---------------- xs phase (256 rows/block) ----------------
        int rowbase_blk = blockIdx.x * 256;
        // zero agg rows owned by this block (wide stores, 64 rows/iter)
        {
            const short8 z = short8{0,0,0,0,0,0,0,0};
#pragma unroll
            for (int it = 0; it < 4; ++it) {
                int r0 = rowbase_blk + it * 64;
                int row0 = r0 + (tid >> 2);
                if (row0 < NNODES) {
                    size_t base = (size_t)r0 * DD + tid * 16;
                    *(short8*)(pr.agg + base) = z;
                    *(short8*)(pr.agg + base + 8) = z;
                }
            }
        }
        // stage Ws as bf16 once (division-free, f32x2 loads, dword LDS stores)
        for (int idx = tid; idx < (AA * DD) / 2; idx += 256) {
            int a = idx >> 5, d2 = (idx & 31) * 2;
            f32x2 x = *(const f32x2*)(pr.Ws_W + a * 64 + d2);
            *reinterpret_cast<unsigned*>(&W[a * 72 + d2]) = pack2bf(x[0], x[1]);
        }
        __syncthreads();
#pragma unroll
        for (int it = 0; it < 4; ++it) {
            int rowbase = rowbase_blk + it * 64 + wave * 16;
            int row_a = rowbase + l15;
            f32x4 acc[4];
            for (int t = 0; t < 4; ++t) { acc[t][0]=acc[t][1]=acc[t][2]=acc[t][3]=0.f; }
#pragma unroll
            for (int ks = 0; ks < 2; ++ks) {
                int ka = ks * 32 + quad * 8;
                short8 afrag;
                if (row_a < NNODES) {
                    afrag = load8_cvt(pr.hidden + (size_t)row_a * DD + ka);
                    *(short8*)(pr.hidden_bf + (size_t)row_a * DD + ka) = afrag;
                } else {
                    afrag = short8{0,0,0,0,0,0,0,0};
                }
#pragma unroll
                for (int t = 0; t < 4; ++t) {
                    short8 bfrag = *(const short8*)&W[(t * 16 + l15) * 72 + ka];
                    acc[t] = __builtin_amdgcn_mfma_f32_16x16x32_bf16(afrag, bfrag, acc[t], 0, 0, 0);
                }
            }
            // epilogue: stage -> wide stores (2 short8 stores/lane, coalesced)
            // (same-wave DS ops are ordered: safe to rewrite st each iteration)
#pragma unroll
            for (int t = 0; t < 4; ++t)
#pragma unroll
                for (int r = 0; r < 4; ++r)
                    st[(quad * 4 + r) * 72 + t * 16 + l15] = (short)f2bf(acc[t][r]);
            asm volatile("s_waitcnt lgkmcnt(0)" ::: "memory");
#pragma unroll
            for (int i = 0; i < 2; ++i) {
                int rr = i * 8 + (lane >> 3);
                int cc = (lane & 7) * 8;
                int grow = rowbase + rr;
                if (grow < NNODES) {
                    short8 v = *(short8*)&st[rr * 72 + cc];
                    *(short8*)&pr.Xs[(size_t)grow * AA + cc] = v;
                }
            }
        }
    } else {
        // ---------------- p phase (256 pairs/block) ----------------
        int pairblk = (blockIdx.x - XSB4) * 256;
        // stage W3 = [Wq|Wr|Wqr] as bf16 once
#pragma unroll
        for (int m = 0; m < 3; ++m) {
            const float* src = (m == 0) ? pr.Wq_W : (m == 1) ? pr.Wr_W : pr.Wqr_W;
            for (int idx = tid; idx < (AA * DD) / 2; idx += 256) {
                int a = idx >> 5, d2 = (idx & 31) * 2;
                f32x2 x = *(const f32x2*)(src + a * 64 + d2);
                *reinterpret_cast<unsigned*>(&W[a * 200 + m * 64 + d2]) =
                    pack2bf(x[0], x[1]);
            }
        }
        float bvals[4];
#pragma unroll
        for (int t = 0; t < 4; ++t) bvals[t] = pr.Ws_b[t * 16 + l15];
        __syncthreads();
#pragma unroll
        for (int it = 0; it < 4; ++it) {
            int pairbase = pairblk + it * 64 + wave * 16;
            int mypair = pairbase + l15;
            int q = mypair / RN;
            int r = mypair - q * RN;
            const float* hq = pr.q_emb + (size_t)q * DD;
            const float* hr = pr.rela  + (size_t)r * DD;
            f32x4 acc[4];
#pragma unroll
            for (int t = 0; t < 4; ++t) {
                acc[t][0] = acc[t][1] = acc[t][2] = acc[t][3] = bvals[t];
            }
#pragma unroll
            for (int ks = 0; ks < 6; ++ks) {
                int ka = ks * 32 + quad * 8;
                short8 afrag;
                if (ka < 64)       afrag = load8_cvt(hq + ka);
                else if (ka < 128) afrag = load8_cvt(hr + (ka - 64));
                else               afrag = load8_cvt_prod(hq + (ka - 128), hr + (ka - 128));
#pragma unroll
                for (int t = 0; t < 4; ++t) {
                    short8 bfrag = *(const short8*)&W[(t * 16 + l15) * 200 + ka];
                    acc[t] = __builtin_amdgcn_mfma_f32_16x16x32_bf16(afrag, bfrag, acc[t], 0, 0, 0);
                }
            }
            // epilogue: stage -> wide stores (no bounds check; PB4 grid is exact)
#pragma unroll
            for (int t = 0; t < 4; ++t)
#pragma unroll
                for (int rg = 0; rg < 4; ++rg)
                    st[(quad * 4 + rg) * 72 + t * 16 + l15] = (short)f2bf(acc[t][rg]);
            asm volatile("s_waitcnt lgkmcnt(0)" ::: "memory");
#pragma unroll
            for (int i = 0; i < 2; ++i) {
                int rr = i * 8 + (lane >> 3);
                int cc = (lane & 7) * 8;
                int prow = pairbase + rr;
                short8 v = *(short8*)&st[rr * 72 + cc];
                *(short8*)&pr.P[(size_t)prow * AA + cc] = v;
            }
        }
    }
}

// ---------------------------------------------------------------------------
// K_EDGE (round-4 exact, 58.4us proven — frozen; at the L2 atomic-op ceiling):
//         8 edges per wave. Alpha phase: 8 lanes/edge, 16B loads, 3-step
//         reduce. Message phase: 4 passes of 32-lanes/edge so each atomic
//         instruction covers one edge's 128B agg row CONTIGUOUSLY
//         (round-3 lesson: strided pk atomics cost ~16B HBM write each).
// ---------------------------------------------------------------------------
__global__ void k_edge(Params pr) {
    int tid  = threadIdx.x;
    int lane = tid & 63;
    int l8   = tid & 7;
    int g    = lane >> 3;                        // edge group within wave (0..7)
    int wave = tid >> 6;
    size_t ewave = (size_t)blockIdx.x * 32 + wave * 8;   // first edge of wave
    size_t e = ewave + g;                        // this group's edge

    // cooperative coalesced load of this wave's 8 edge rows (48 ints)
    const int* ebase = pr.edges + ewave * 6;
    int eval = (lane < 48) ? ebase[lane] : 0;
    int q   = __shfl(eval, g * 6 + 0, 64);
    int r   = __shfl(eval, g * 6 + 2, 64);
    int sub = __shfl(eval, g * 6 + 4, 64);
    int qr  = q * RN + r;
    int c8  = l8 * 8;

    // ---- alpha phase: 8 lanes/edge, 16B gathers of Xs/P rows ----
    short8 xs8 = *(const short8*)(pr.Xs + (size_t)sub * AA + c8);
    short8 pp8 = *(const short8*)(pr.P  + (size_t)qr  * AA + c8);
    f32x4 waA = *(const f32x4*)(pr.wa_W + c8);
    f32x4 waB = *(const f32x4*)(pr.wa_W + c8 + 4);

    uint4v xu = __builtin_bit_cast(uint4v, xs8);
    uint4v pu = __builtin_bit_cast(uint4v, pp8);
    f32x2 acc2; acc2[0] = 0.f; acc2[1] = 0.f;
#pragma unroll
    for (int j = 0; j < 4; ++j) {
        f32x2 a = bfpair2f(xu[j]);
        f32x2 b = bfpair2f(pu[j]);
        f32x2 s = a + b;                       // packable v_pk_add_f32
        float wlo = (j < 2) ? waA[2*j]     : waB[2*j - 4];
        float whi = (j < 2) ? waA[2*j + 1] : waB[2*j - 3];
        acc2[0] += fmaxf(s[0], 0.f) * wlo;
        acc2[1] += fmaxf(s[1], 0.f) * whi;
    }
    float v = acc2[0] + acc2[1];
    v += __shfl_xor(v, 1, 64);
    v += __shfl_xor(v, 2, 64);
    v += __shfl_xor(v, 4, 64);
    float alpha = 1.f / (1.f + __expf(-(v + pr.wa_b[0])));
    if (l8 == 0) pr.alpha_out[e] = alpha;

    // ---- message phase: 4 passes, 32 lanes/edge, contiguous atomics ----
    int half = lane >> 5;                        // 0..1: which edge this pass
    int c2   = (lane & 31) * 2;                  // contiguous column pair
#pragma unroll
    for (int pass = 0; pass < 4; ++pass) {
        int ge    = pass * 2 + half;             // edge group handled this pass
        int sub_p = __shfl(eval, ge * 6 + 4, 64);
        int r_p   = __shfl(eval, ge * 6 + 2, 64);
        int obj_p = __shfl(eval, ge * 6 + 5, 64);
        float al  = __shfl(alpha, ge * 8, 64);   // all lanes of group ge hold alpha
        unsigned hs_u = *(const unsigned*)&pr.hidden_bf[(size_t)sub_p * DD + c2];
        f32x2 hs = bfpair2f(hs_u);
        f32x2 hr = *(const f32x2*)&pr.rela[(size_t)r_p * DD + c2];
        atomic_pk_add_bf16_u(pr.agg + (size_t)obj_p * DD + c2,
                             pack2bf(al * hs[0] * hr[0], al * hs[1] * hr[1]));
    }
}

// ---------------------------------------------------------------------------
// K_OUT: out = agg @ Wh^T (MFMA, K=64; agg bf16). 256 rows/block, Wh staged
//        once, 4 row-tile iterations. LDS-staged f32x4 stores.
// ---------------------------------------------------------------------------
__global__ void k_out(Params pr) {
    __shared__ short W[OO * 72];           // 9216 B
    __shared__ float stF[4][16 * 68];      // 17408 B, per-wave 16x64 f32 tile (+pad)
    int tid = threadIdx.x;
    for (int idx = tid; idx < (OO * DD) / 2; idx += 256) {
        int o = idx >> 5, d2 = (idx & 31) * 2;
        f32x2 x = *(const f32x2*)(pr.Wh_W + o * 64 + d2);
        *reinterpret_cast<unsigned*>(&W[o * 72 + d2]) = pack2bf(x[0], x[1]);
    }
    __syncthreads();
    int wave = tid >> 6, lane = tid & 63;
    int quad = lane >> 4, l15 = lane & 15;
    float* st = stF[wave];

#pragma unroll
    for (int it = 0; it < 4; ++it) {
        int rowbase = blockIdx.x * 256 + it * 64 + wave * 16;
        int row_a = rowbase + l15;
        f32x4 acc[4];
        for (int t = 0; t < 4; ++t) { acc[t][0]=acc[t][1]=acc[t][2]=acc[t][3]=0.f; }
#pragma unroll
        for (int ks = 0; ks < 2; ++ks) {
            int ka = ks * 32 + quad * 8;
            short8 afrag;
            if (row_a < NNODES) afrag = *(const short8*)(pr.agg + (size_t)row_a * DD + ka);
            else                afrag = short8{0,0,0,0,0,0,0,0};
#pragma unroll
            for (int t = 0; t < 4; ++t) {
                short8 bfrag = *(const short8*)&W[(t * 16 + l15) * 72 + ka];
                acc[t] = __builtin_amdgcn_mfma_f32_16x16x32_bf16(afrag, bfrag, acc[t], 0, 0, 0);
            }
        }
        // epilogue: stage -> 4 coalesced f32x4 stores/lane
#pragma unroll
        for (int t = 0; t < 4; ++t)
#pragma unroll
            for (int r = 0; r < 4; ++r)
                st[(quad * 4 + r) * 68 + t * 16 + l15] = acc[t][r];
        asm volatile("s_waitcnt lgkmcnt(0)" ::: "memory");
#pragma unroll
        for (int i = 0; i < 4; ++i) {
            int rr = i * 4 + (lane >> 4);
            int cc = (lane & 15) * 4;
            int grow = rowbase + rr;
            if (grow < NNODES) {
                f32x4 v = *(f32x4*)&st[rr * 68 + cc];
                *(f32x4*)&pr.out[(size_t)grow * OO + cc] = v;
            }
        }
    }
}

// ---------------------------------------------------------------------------
extern "C" void kernel_launch(void* const* d_in, const int* in_sizes, int n_in,
                              void* d_out, int out_size, void* d_ws, size_t ws_size,
                              hipStream_t stream) {
    Params pr;
    pr.q_emb  = (const float*)d_in[1];
    pr.rela   = (const float*)d_in[2];
    pr.hidden = (const float*)d_in[3];
    pr.edges  = (const int*)d_in[4];
    pr.Ws_W   = (const float*)d_in[6];
    pr.Ws_b   = (const float*)d_in[7];
    pr.Wr_W   = (const float*)d_in[8];
    pr.Wq_W   = (const float*)d_in[9];
    pr.Wqr_W  = (const float*)d_in[10];
    pr.wa_W   = (const float*)d_in[11];
    pr.wa_b   = (const float*)d_in[12];
    pr.Wh_W   = (const float*)d_in[13];

    short* Xs        = (short*)d_ws;                         // N*A   bf16
    short* P         = Xs + (size_t)NNODES * AA;             // Q*R*A bf16
    short* hidden_bf = P + (size_t)QN * RN * AA;             // N*D   bf16
    short* agg       = hidden_bf + (size_t)NNODES * DD;      // N*D   bf16
    pr.Xs = Xs; pr.P = P; pr.hidden_bf = hidden_bf; pr.agg = agg;

    pr.out       = (float*)d_out;                            // hidden_new (N*O)
    pr.alpha_out = pr.out + (size_t)NNODES * OO;             // alpha (E)

    k_pre<<<XSB4 + PB4, 256, 0, stream>>>(pr);
    k_edge<<<EB, 256, 0, stream>>>(pr);
    k_out<<<OB4, 256, 0, stream>>>(pr);
}